// Round 7
// baseline (374.795 us; speedup 1.0000x reference)
//
#include <hip/hip_runtime.h>
#include <stdint.h>

using short8   = __attribute__((ext_vector_type(8))) short;
using short4_  = __attribute__((ext_vector_type(4))) short;
using float4_  = __attribute__((ext_vector_type(4))) float;
using ushort4_ = __attribute__((ext_vector_type(4))) unsigned short;
typedef unsigned int  uint;
typedef unsigned short ushort;

// ---------- bf16 helpers ----------
__device__ __forceinline__ float bf2f(ushort b) {
  uint u = ((uint)b) << 16;
  return __builtin_bit_cast(float, u);
}
__device__ __forceinline__ ushort f2bf(float f) {
  uint u = __builtin_bit_cast(uint, f);
  u = u + 0x7fffu + ((u >> 16) & 1u);   // RTNE
  return (ushort)(u >> 16);
}

// ---------- constants ----------
#define NN   216
#define NSQ  46656
#define PADV (-3.0e6f)

#if __has_builtin(__builtin_amdgcn_mfma_f32_16x16x16bf16_1k)
  #define HAVE_MFMA16 1
  #define MFMA16(a, b, c) __builtin_amdgcn_mfma_f32_16x16x16bf16_1k(a, b, c, 0, 0, 0)
#elif __has_builtin(__builtin_amdgcn_mfma_f32_16x16x16_bf16)
  #define HAVE_MFMA16 1
  #define MFMA16(a, b, c) __builtin_amdgcn_mfma_f32_16x16x16_bf16(a, b, c, 0, 0, 0)
#else
  #define HAVE_MFMA16 0
#endif

// weight arena element offsets
#define WA_WQKV   0
#define WA_BQKV   110592
#define WA_WPROJ  111168
#define WA_BPROJ  148032
#define WA_PPW    148224
#define WA_PPB    148260
#define WA_G1     148272
#define WA_B1     148284
#define WA_W1     148296
#define WA_WB1    148440
#define WA_G2     148452
#define WA_B2     148464
#define WA_W2     148476
#define WA_WB2    148620
#define WA_G3     148632
#define WA_B3     148644
#define WA_W3     148656
#define WA_WB3    148728
#define WA_TOTAL  148740

// =====================================================================
// 0) dtype detector
// =====================================================================
__global__ void detect_kernel(const uint* __restrict__ x, int* __restrict__ flag) {
  int lane = threadIdx.x;
  uint w = x[lane];
  ushort lo = (ushort)(w & 0xffffu);
  int e = (lo >> 7) & 0xff;
  int sane = (lo == 0 || (e >= 0x60 && e <= 0x9f)) ? 1 : 0;
  unsigned long long b = __ballot(sane);
  if (lane == 0) flag[0] = (__popcll(b) >= 56) ? 0 : 1;
}

// =====================================================================
// 0b) weight conversion into canonical bf16 arena
// =====================================================================
struct SrcPtrs { const void* p[18]; };

__global__ void convert_kernel(SrcPtrs sp, ushort* __restrict__ dst,
                               const int* __restrict__ flag) {
  constexpr int OFF[19] = {WA_WQKV, WA_BQKV, WA_WPROJ, WA_BPROJ, WA_PPW, WA_PPB,
                           WA_G1, WA_B1, WA_W1, WA_WB1, WA_G2, WA_B2, WA_W2,
                           WA_WB2, WA_G3, WA_B3, WA_W3, WA_WB3, WA_TOTAL};
  int t = blockIdx.x * 256 + threadIdx.x;
  if (t >= WA_TOTAL) return;
  int a = 0;
#pragma unroll
  for (int i = 1; i < 18; ++i) a += (t >= OFF[i]) ? 1 : 0;
  int local = t - OFF[a];
  const void* s = sp.p[a];
  ushort v;
  if (flag[0]) v = f2bf(((const float*)s)[local]);
  else         v = ((const ushort*)s)[local];
  dst[t] = v;
}

// =====================================================================
// 0c) pack W into per-tile B-fragment-linear blobs
//     blob 0..5: qkv (z*2 + half), blob 6..7: proj halves
//     blob layout: chunk s = (kk*6+nt)*64 + quad*16 + l16; 8 ushorts/chunk
// =====================================================================
__global__ void packw_kernel(const ushort* __restrict__ wa, ushort* __restrict__ wp) {
  int c = blockIdx.x * 256 + threadIdx.x;
  if (c >= 8 * 2304) return;
  int blob = c / 2304, s = c - blob * 2304;
  int kk = s / 384, r = s - kk * 384;
  int nt = r >> 6, l = r & 63;
  int l16 = l & 15, qd = l >> 4;
  int col, base;
  if (blob < 6) { int z = blob >> 1, half = blob & 1;
                  col = z * 192 + half * 96 + nt * 16 + l16; base = WA_WQKV; }
  else          { col = (blob - 6) * 96 + nt * 16 + l16;     base = WA_WPROJ; }
  short8 pk = *(const short8*)(wa + base + (size_t)col * 192 + kk * 32 + qd * 8);
  *(short8*)(wp + (size_t)c * 8) = pk;
}

// =====================================================================
// 0d) pack y into A-fragment-linear tiles (replaces cvt)
//     chunk c: tile = c/3072; kk = (c%3072)/512; rowhi = (c%512)/64;
//              q = (c%64)/16; l16 = c%16  -> row = rowhi*16+l16
//     dst[c*8 + j] = A[tile*128+row][kk*32+q*8+j]   (contiguous writes)
// =====================================================================
__global__ __launch_bounds__(256) void packa_kernel(const void* __restrict__ src,
                                                    ushort* __restrict__ dst,
                                                    const int* __restrict__ flag) {
  int c = blockIdx.x * 256 + threadIdx.x;   // 5184*256 = 1,327,104 chunks
  int tile = c / 3072, cc = c - tile * 3072;
  int kk = cc / 512, c2 = cc - kk * 512;
  int rowhi = c2 / 64, c3 = c2 - rowhi * 64;
  int q = c3 >> 4, l16 = c3 & 15;
  size_t M = (size_t)tile * 128 + rowhi * 16 + l16;
  size_t so = M * 192 + kk * 32 + q * 8;
  short8 pk;
  if (flag[0]) {
    float4_ lo = *(const float4_*)((const float*)src + so);
    float4_ hi = *(const float4_*)((const float*)src + so + 4);
#pragma unroll
    for (int j = 0; j < 4; ++j) {
      pk[j]     = (short)f2bf(lo[j]);
      pk[4 + j] = (short)f2bf(hi[j]);
    }
  } else {
    pk = *(const short8*)((const ushort*)src + so);
  }
  *(short8*)(dst + (size_t)c * 8) = pk;
}

// =====================================================================
// pos MLP as device function (computed in-block by rpbfrag)
// =====================================================================
__device__ __forceinline__ void ln_relu(const float* p, const ushort* g,
                                        const ushort* b, float* r) {
  float m = 0.f;
#pragma unroll
  for (int t = 0; t < 12; ++t) m += p[t];
  m *= (1.f / 12.f);
  float v = 0.f;
#pragma unroll
  for (int t = 0; t < 12; ++t) { float d = p[t] - m; v += d * d; }
  v *= (1.f / 12.f);
  float inv = rsqrtf(v + 1e-5f);
#pragma unroll
  for (int t = 0; t < 12; ++t) {
    float z = (p[t] - m) * inv * bf2f(g[t]) + bf2f(b[t]);
    r[t] = fmaxf(z, 0.f);
  }
}

__device__ void pos_mlp_row(const ushort* wa, int m, float* out6) {
  const ushort* pw  = wa + WA_PPW;  const ushort* pb  = wa + WA_PPB;
  const ushort* g1  = wa + WA_G1;   const ushort* b1  = wa + WA_B1;
  const ushort* w1  = wa + WA_W1;   const ushort* wb1 = wa + WA_WB1;
  const ushort* g2  = wa + WA_G2;   const ushort* b2  = wa + WA_B2;
  const ushort* w2  = wa + WA_W2;   const ushort* wb2 = wa + WA_WB2;
  const ushort* g3  = wa + WA_G3;   const ushort* b3  = wa + WA_B3;
  const ushort* w3  = wa + WA_W3;   const ushort* wb3 = wa + WA_WB3;
  int ih = m / 121, rem = m - ih * 121;
  int iw = rem / 11, id = rem - iw * 11;
  float fh = (float)(ih - 5), fw = (float)(iw - 5), fd = (float)(id - 5);
  float p[12], r[12], q[12];
#pragma unroll
  for (int t = 0; t < 12; ++t)
    p[t] = fh * bf2f(pw[t * 3]) + fw * bf2f(pw[t * 3 + 1]) +
           fd * bf2f(pw[t * 3 + 2]) + bf2f(pb[t]);
  ln_relu(p, g1, b1, r);
#pragma unroll
  for (int t = 0; t < 12; ++t) {
    float s = bf2f(wb1[t]);
#pragma unroll
    for (int u = 0; u < 12; ++u) s += r[u] * bf2f(w1[t * 12 + u]);
    q[t] = s;
  }
  ln_relu(q, g2, b2, r);
#pragma unroll
  for (int t = 0; t < 12; ++t) {
    float s = bf2f(wb2[t]);
#pragma unroll
    for (int u = 0; u < 12; ++u) s += r[u] * bf2f(w2[t * 12 + u]);
    p[t] = s;
  }
  ln_relu(p, g3, b3, r);
#pragma unroll
  for (int h = 0; h < 6; ++h) {
    float s = bf2f(wb3[h]);
#pragma unroll
    for (int u = 0; u < 12; ++u) s += r[u] * bf2f(w3[h * 12 + u]);
    out6[h] = s;
  }
}

// =====================================================================
// 2a) rpb fragments (transposed S^T layout), pos MLP computed in-block
// =====================================================================
__global__ __launch_bounds__(256) void rpbfrag_kernel(const ushort* __restrict__ wa,
                                                      ushort* __restrict__ out) {
  __shared__ float pos_l[1331 * 6];
  for (int m = threadIdx.x; m < 1331; m += 256) {
    float o6[6];
    pos_mlp_row(wa, m, o6);
#pragma unroll
    for (int h = 0; h < 6; ++h) pos_l[m * 6 + h] = o6[h];
  }
  __syncthreads();

  int tgl = blockIdx.x * 256 + threadIdx.x;
  if (tgl >= 6 * 196 * 64) return;
  int lane = tgl & 63;
  int tj   = (tgl >> 6) % 196;
  int h    = (tgl >> 6) / 196;
  int tt = tj / 14, jt = tj - tt * 14;
  int l16 = lane & 15, quad = lane >> 4;
  int i = tt * 16 + l16;
  int jbase = jt * 16 + quad * 4;
  ushort4_ o;
  if (i < 216 && jbase < 216) {
    int h1 = i / 36, r1 = i - h1 * 36, w1 = r1 / 6, d1 = r1 - w1 * 6;
#pragma unroll
    for (int r = 0; r < 4; ++r) {
      int j = jbase + r;
      int h2 = j / 36, r2 = j - h2 * 36, w2 = r2 / 6, d2 = r2 - w2 * 6;
      int idx = ((h1 - h2 + 5) * 11 + (w1 - w2 + 5)) * 11 + (d1 - d2 + 5);
      o[r] = f2bf(pos_l[idx * 6 + h]);
    }
  } else {
#pragma unroll
    for (int r = 0; r < 4; ++r) o[r] = f2bf(PADV);
  }
  *(ushort4_*)(out + (size_t)tgl * 4) = o;
}

// =====================================================================
// 2b) mask fragments, transposed layout
// =====================================================================
__global__ void maskfrag_kernel(const void* __restrict__ maskv,
                                const int* __restrict__ flag,
                                ushort* __restrict__ out) {
  int tgl = blockIdx.x * 256 + threadIdx.x;
  if (tgl >= 64 * 196 * 64) return;
  bool mf32 = flag[0] != 0;
  int lane = tgl & 63;
  int tj   = (tgl >> 6) % 196;
  int g    = (tgl >> 6) / 196;
  int tt = tj / 14, jt = tj - tt * 14;
  int l16 = lane & 15, quad = lane >> 4;
  int i = tt * 16 + l16;
  int jbase = jt * 16 + quad * 4;
  ushort4_ o;
  if (i < 216 && jbase < 216) {
    int mi = i * 216 + jbase;
    if (mf32) {
      float4_ mv = *(const float4_*)((const float*)maskv + (size_t)g * NSQ + mi);
#pragma unroll
      for (int r = 0; r < 4; ++r) o[r] = f2bf(mv[r]);
    } else {
      o = *(const ushort4_*)((const ushort*)maskv + (size_t)g * NSQ + mi);
    }
  } else {
#pragma unroll
    for (int r = 0; r < 4; ++r) o[r] = f2bf(PADV);
  }
  *(ushort4_*)(out + (size_t)tgl * 4) = o;
}

// =====================================================================
// 3) GEMM v3: M-tile 128, N-tile 96, K=192.
//    A: packed-coalesced (yf) for z=1,2; row-major for z=0 / proj.
//    B: contiguous copy from packed blob -> conflict-free LDS.
// =====================================================================
__global__ __launch_bounds__(256, 2) void gemm_kernel(
    const void* __restrict__ Arow,        // x (qkv z=0) / opre (proj)
    const ushort* __restrict__ Apack,     // yf (qkv z=1,2)
    const ushort* __restrict__ wpacked,
    const ushort* __restrict__ bias,
    void* __restrict__ dq, void* __restrict__ dk, void* __restrict__ dv,
    const int* __restrict__ flag, int is_proj) {
  __shared__ __align__(16) ushort b_lds[2304 * 8];

  int tid = threadIdx.x;
  int tile = blockIdx.x;
  int m0 = tile * 128;
  int half = blockIdx.y;
  int n0 = half * 96;
  int z  = blockIdx.z;
  int blob = is_proj ? (6 + half) : (z * 2 + half);
  float scale = (!is_proj && z == 0) ? 0.17677669529663687f : 1.0f;
  void* dst = (z == 0) ? dq : (z == 1 ? dk : dv);
  int fl = flag[0];
  bool a_packed = (!is_proj) && (z != 0);
  bool f32path = (!is_proj) && (z == 0) && (fl != 0);
  bool o_f32 = is_proj && (fl != 0);

  int lane = tid & 63, w = tid >> 6;
  int l16 = lane & 15, quad = lane >> 4;

  // ---- A fragments ----
  short8 af[6][2];
  if (a_packed) {
    const ushort* tb = Apack + (size_t)tile * 24576 + lane * 8;
#pragma unroll
    for (int kk = 0; kk < 6; ++kk)
#pragma unroll
      for (int mt = 0; mt < 2; ++mt)
        af[kk][mt] = *(const short8*)(tb + kk * 4096 + (w * 2 + mt) * 512);
  } else if (f32path) {
#pragma unroll
    for (int kk = 0; kk < 6; ++kk)
#pragma unroll
      for (int mt = 0; mt < 2; ++mt) {
        const float* Af = (const float*)Arow +
            (size_t)(m0 + w * 32 + mt * 16 + l16) * 192 + kk * 32 + quad * 8;
        float4_ lo = *(const float4_*)Af;
        float4_ hi = *(const float4_*)(Af + 4);
#pragma unroll
        for (int j = 0; j < 4; ++j) {
          af[kk][mt][j]     = (short)f2bf(lo[j]);
          af[kk][mt][4 + j] = (short)f2bf(hi[j]);
        }
      }
  } else {
#pragma unroll
    for (int kk = 0; kk < 6; ++kk)
#pragma unroll
      for (int mt = 0; mt < 2; ++mt)
        af[kk][mt] = *(const short8*)((const ushort*)Arow +
            (size_t)(m0 + w * 32 + mt * 16 + l16) * 192 + kk * 32 + quad * 8);
  }

  // ---- stage B: contiguous blob copy (fully coalesced, conflict-free) ----
  {
    const ushort* wb = wpacked + (size_t)blob * 18432;
#pragma unroll
    for (int it = 0; it < 9; ++it) {
      int s = tid + it * 256;
      *(short8*)(b_lds + s * 8) = *(const short8*)(wb + s * 8);
    }
  }
  __syncthreads();

  float4_ acc[2][6];
#pragma unroll
  for (int mt = 0; mt < 2; ++mt)
#pragma unroll
    for (int nt = 0; nt < 6; ++nt) acc[mt][nt] = (float4_){0.f, 0.f, 0.f, 0.f};

#pragma unroll
  for (int kk = 0; kk < 6; ++kk) {
    short8 bfr[6];
#pragma unroll
    for (int nt = 0; nt < 6; ++nt)
      bfr[nt] = *(const short8*)(b_lds + ((kk * 6 + nt) * 64 + lane) * 8);
#pragma unroll
    for (int mt = 0; mt < 2; ++mt)
#pragma unroll
      for (int nt = 0; nt < 6; ++nt)
        acc[mt][nt] = __builtin_amdgcn_mfma_f32_16x16x32_bf16(af[kk][mt], bfr[nt], acc[mt][nt], 0, 0, 0);
  }

#pragma unroll
  for (int mt = 0; mt < 2; ++mt) {
#pragma unroll
    for (int nt = 0; nt < 6; ++nt) {
      int lcol = n0 + nt * 16 + l16;
      float bv = bf2f(bias[(is_proj ? 0 : z * 192) + lcol]);
#pragma unroll
      for (int r = 0; r < 4; ++r) {
        int grow = m0 + w * 32 + mt * 16 + quad * 4 + r;
        float val = (acc[mt][nt][r] + bv) * scale;
        if (is_proj) {
          if (o_f32) ((float*)dst)[(size_t)grow * 192 + lcol] = val;
          else       ((ushort*)dst)[(size_t)grow * 192 + lcol] = f2bf(val);
        } else {
          int bb = grow / 216;
          int nn2 = grow - bb * 216;
          int hh = lcol >> 5, dd = lcol & 31;
          ((ushort*)dst)[(((size_t)bb * 6 + hh) * 216 + nn2) * 32 + dd] = f2bf(val);
        }
      }
    }
  }
}

// =====================================================================
// 4) fused attention v2 (S^T trick)
// =====================================================================
__global__ __launch_bounds__(256) void attn_kernel(
    const ushort* __restrict__ q, const ushort* __restrict__ k,
    const ushort* __restrict__ v, const ushort* __restrict__ rpbf,
    const ushort* __restrict__ maskf, ushort* __restrict__ opre) {
#if HAVE_MFMA16
  __shared__ __align__(16) ushort vfrag[28 * 64 * 4];
#else
  __shared__ __align__(16) ushort vfrag[14 * 64 * 8];
#endif

  int bid = blockIdx.x;
  int b = bid / 6, h = bid - b * 6;
  int g = b & 63;
  int tid = threadIdx.x, lane = tid & 63, w = tid >> 6;
  int l16 = lane & 15, quad = lane >> 4;

  const ushort* qh = q + (size_t)(b * 6 + h) * 6912;
  const ushort* kh = k + (size_t)(b * 6 + h) * 6912;
  const ushort* vh = v + (size_t)(b * 6 + h) * 6912;

#if HAVE_MFMA16
  for (int pos = tid; pos < 1792; pos += 256) {
    int chunk = pos >> 6, l = pos & 63;
    int kt = chunk >> 1, dh = chunk & 1;
    int qd = l >> 4, lv = l & 15;
    ushort4_ tmp;
#pragma unroll
    for (int j = 0; j < 4; ++j)
      tmp[j] = vh[(kt * 16 + qd * 4 + j) * 32 + dh * 16 + lv];
    *(ushort4_*)(vfrag + pos * 4) = tmp;
  }
#else
  for (int pos = tid; pos < 896; pos += 256) {
    int chunk = pos >> 6, l = pos & 63;
    int kt2 = chunk >> 1, dh = chunk & 1;
    int qd = l >> 4, lv = l & 15;
    short8 tmp;
#pragma unroll
    for (int j = 0; j < 8; ++j)
      tmp[j] = (short)vh[(kt2 * 32 + qd * 8 + j) * 32 + dh * 16 + lv];
    *(short8*)(vfrag + pos * 8) = tmp;
  }
#endif
  __syncthreads();

  for (int t = w; t < 14; t += 4) {
    int r0 = t * 16;
    const ushort* rf = rpbf  + ((size_t)(h * 196 + t * 14) * 64 + lane) * 4;
    const ushort* mf = maskf + ((size_t)(g * 196 + t * 14) * 64 + lane) * 4;
    short8 aq = *(const short8*)(qh + (r0 + l16) * 32 + quad * 8);

    float4_ st[14];
#pragma unroll
    for (int jt = 0; jt < 14; ++jt) {
      ushort4_ rb = *(const ushort4_*)(rf + jt * 256);
      ushort4_ mb = *(const ushort4_*)(mf + jt * 256);
      float4_ cin;
#pragma unroll
      for (int r = 0; r < 4; ++r) cin[r] = bf2f(rb[r]) + bf2f(mb[r]);
      short8 bk = *(const short8*)(kh + (jt * 16 + l16) * 32 + quad * 8);
      st[jt] = __builtin_amdgcn_mfma_f32_16x16x32_bf16(bk, aq, cin, 0, 0, 0);
    }

    float mx = -1e30f;
#pragma unroll
    for (int jt = 0; jt < 14; ++jt)
#pragma unroll
      for (int r = 0; r < 4; ++r) mx = fmaxf(mx, st[jt][r]);
    mx = fmaxf(mx, __shfl_xor(mx, 16));
    mx = fmaxf(mx, __shfl_xor(mx, 32));
    float sum = 0.f;
#pragma unroll
    for (int jt = 0; jt < 14; ++jt)
#pragma unroll
      for (int r = 0; r < 4; ++r) {
        float pe = __expf(st[jt][r] - mx);
        st[jt][r] = pe;
        sum += pe;
      }
    sum += __shfl_xor(sum, 16);
    sum += __shfl_xor(sum, 32);
    float inv = 1.0f / sum;

    float4_ o0 = (float4_){0.f, 0.f, 0.f, 0.f};
    float4_ o1 = (float4_){0.f, 0.f, 0.f, 0.f};

#if HAVE_MFMA16
#pragma unroll
    for (int kt = 0; kt < 14; ++kt) {
      short4_ pa;
#pragma unroll
      for (int r = 0; r < 4; ++r) pa[r] = (short)f2bf(st[kt][r]);
      short4_ vb0 = *(const short4_*)(vfrag + ((kt * 2 + 0) * 64 + lane) * 4);
      short4_ vb1 = *(const short4_*)(vfrag + ((kt * 2 + 1) * 64 + lane) * 4);
      o0 = MFMA16(pa, vb0, o0);
      o1 = MFMA16(pa, vb1, o1);
    }
#else
#pragma unroll
    for (int kt2 = 0; kt2 < 7; ++kt2) {
      uint pe0 = ((uint)f2bf(st[2*kt2][0])) | (((uint)f2bf(st[2*kt2][1])) << 16);
      uint pe1 = ((uint)f2bf(st[2*kt2][2])) | (((uint)f2bf(st[2*kt2][3])) << 16);
      uint po0 = ((uint)f2bf(st[2*kt2+1][0])) | (((uint)f2bf(st[2*kt2+1][1])) << 16);
      uint po1 = ((uint)f2bf(st[2*kt2+1][2])) | (((uint)f2bf(st[2*kt2+1][3])) << 16);
      int slo = (((2 * quad) & 3) << 4) | l16;
      int shi = (((2 * quad + 1) & 3) << 4) | l16;
      uint e_lo0 = __shfl((int)pe0, slo), e_lo1 = __shfl((int)pe1, slo);
      uint o_lo0 = __shfl((int)po0, slo), o_lo1 = __shfl((int)po1, slo);
      uint e_hi0 = __shfl((int)pe0, shi), e_hi1 = __shfl((int)pe1, shi);
      uint o_hi0 = __shfl((int)po0, shi), o_hi1 = __shfl((int)po1, shi);
      uint lo0 = (quad < 2) ? e_lo0 : o_lo0, lo1 = (quad < 2) ? e_lo1 : o_lo1;
      uint hi0 = (quad < 2) ? e_hi0 : o_hi0, hi1 = (quad < 2) ? e_hi1 : o_hi1;
      uint4 paw = {lo0, lo1, hi0, hi1};
      short8 pa = __builtin_bit_cast(short8, paw);
      short8 vb0 = *(const short8*)(vfrag + ((kt2 * 2 + 0) * 64 + lane) * 8);
      short8 vb1 = *(const short8*)(vfrag + ((kt2 * 2 + 1) * 64 + lane) * 8);
      o0 = __builtin_amdgcn_mfma_f32_16x16x32_bf16(pa, vb0, o0, 0, 0, 0);
      o1 = __builtin_amdgcn_mfma_f32_16x16x32_bf16(pa, vb1, o1, 0, 0, 0);
    }
#endif

#pragma unroll
    for (int r = 0; r < 4; ++r) {
      float ir = __shfl(inv, quad * 4 + r);
      int i = r0 + quad * 4 + r;
      if (i < 216) {
        size_t base = ((size_t)b * 216 + i) * 192 + h * 32;
        opre[base + l16]      = f2bf(o0[r] * ir);
        opre[base + 16 + l16] = f2bf(o1[r] * ir);
      }
    }
  }
}

// =====================================================================
// launch
// =====================================================================
extern "C" void kernel_launch(void* const* d_in, const int* in_sizes, int n_in,
                              void* d_out, int out_size, void* d_ws, size_t ws_size,
                              hipStream_t stream) {
  (void)in_sizes; (void)n_in; (void)out_size; (void)ws_size;

  char* p = (char*)d_ws;
  int*    flag    = (int*)p;           p += 256;
  ushort* warena  = (ushort*)p;        p += 298240;
  ushort* wpacked = (ushort*)p;        p += 294912;    // 8 * 2304 * 8 * 2
  ushort* rpbf    = (ushort*)p;        p += 602112;
  ushort* maskf   = (ushort*)p;        p += 6422528;
  ushort* yf      = (ushort*)p;        p += 21234688;  // aliased as opre after QKV GEMM
  ushort* qb      = (ushort*)p;        p += 21234688;
  ushort* kb      = (ushort*)p;        p += 21234688;
  ushort* vb      = (ushort*)p;
  ushort* opre    = yf;

  detect_kernel<<<1, 64, 0, stream>>>((const uint*)d_in[0], flag);

  SrcPtrs sp;
  for (int i = 0; i < 18; ++i) sp.p[i] = d_in[3 + i];
  convert_kernel<<<(WA_TOTAL + 255) / 256, 256, 0, stream>>>(sp, warena, flag);
  packw_kernel<<<72, 256, 0, stream>>>(warena, wpacked);

  packa_kernel<<<5184, 256, 0, stream>>>(d_in[1], yf, flag);

  rpbfrag_kernel<<<294, 256, 0, stream>>>(warena, rpbf);
  maskfrag_kernel<<<3136, 256, 0, stream>>>(d_in[2], flag, maskf);

  gemm_kernel<<<dim3(432, 2, 3), 256, 0, stream>>>(
      d_in[0], yf, wpacked, warena + WA_BQKV, qb, kb, vb, flag, 0);

  attn_kernel<<<1536, 256, 0, stream>>>(qb, kb, vb, rpbf, maskf, opre);

  gemm_kernel<<<dim3(432, 2, 1), 256, 0, stream>>>(
      opre, yf, wpacked, warena + WA_BPROJ,
      d_out, d_out, d_out, flag, 1);
}

// Round 8
// 291.965 us; speedup vs baseline: 1.2837x; 1.2837x over previous
//
#include <hip/hip_runtime.h>
#include <stdint.h>

using short8   = __attribute__((ext_vector_type(8))) short;
using short4_  = __attribute__((ext_vector_type(4))) short;
using float4_  = __attribute__((ext_vector_type(4))) float;
using ushort4_ = __attribute__((ext_vector_type(4))) unsigned short;
typedef unsigned int  uint;
typedef unsigned short ushort;

// ---------- bf16 helpers ----------
__device__ __forceinline__ float bf2f(ushort b) {
  uint u = ((uint)b) << 16;
  return __builtin_bit_cast(float, u);
}
__device__ __forceinline__ ushort f2bf(float f) {
  uint u = __builtin_bit_cast(uint, f);
  u = u + 0x7fffu + ((u >> 16) & 1u);   // RTNE
  return (ushort)(u >> 16);
}

// ---------- constants ----------
#define NN   216
#define NSQ  46656
#define PADV (-3.0e6f)

#if __has_builtin(__builtin_amdgcn_mfma_f32_16x16x16bf16_1k)
  #define HAVE_MFMA16 1
  #define MFMA16(a, b, c) __builtin_amdgcn_mfma_f32_16x16x16bf16_1k(a, b, c, 0, 0, 0)
#elif __has_builtin(__builtin_amdgcn_mfma_f32_16x16x16_bf16)
  #define HAVE_MFMA16 1
  #define MFMA16(a, b, c) __builtin_amdgcn_mfma_f32_16x16x16_bf16(a, b, c, 0, 0, 0)
#else
  #define HAVE_MFMA16 0
#endif

// weight arena element offsets
#define WA_WQKV   0
#define WA_BQKV   110592
#define WA_WPROJ  111168
#define WA_BPROJ  148032
#define WA_PPW    148224
#define WA_PPB    148260
#define WA_G1     148272
#define WA_B1     148284
#define WA_W1     148296
#define WA_WB1    148440
#define WA_G2     148452
#define WA_B2     148464
#define WA_W2     148476
#define WA_WB2    148620
#define WA_G3     148632
#define WA_B3     148644
#define WA_W3     148656
#define WA_WB3    148728
#define WA_TOTAL  148740

// =====================================================================
// 0) dtype detector
// =====================================================================
__global__ void detect_kernel(const uint* __restrict__ x, int* __restrict__ flag) {
  int lane = threadIdx.x;
  uint w = x[lane];
  ushort lo = (ushort)(w & 0xffffu);
  int e = (lo >> 7) & 0xff;
  int sane = (lo == 0 || (e >= 0x60 && e <= 0x9f)) ? 1 : 0;
  unsigned long long b = __ballot(sane);
  if (lane == 0) flag[0] = (__popcll(b) >= 56) ? 0 : 1;
}

// =====================================================================
// 0b) weight conversion into canonical bf16 arena
// =====================================================================
struct SrcPtrs { const void* p[18]; };

__global__ void convert_kernel(SrcPtrs sp, ushort* __restrict__ dst,
                               const int* __restrict__ flag) {
  constexpr int OFF[19] = {WA_WQKV, WA_BQKV, WA_WPROJ, WA_BPROJ, WA_PPW, WA_PPB,
                           WA_G1, WA_B1, WA_W1, WA_WB1, WA_G2, WA_B2, WA_W2,
                           WA_WB2, WA_G3, WA_B3, WA_W3, WA_WB3, WA_TOTAL};
  int t = blockIdx.x * 256 + threadIdx.x;
  if (t >= WA_TOTAL) return;
  int a = 0;
#pragma unroll
  for (int i = 1; i < 18; ++i) a += (t >= OFF[i]) ? 1 : 0;
  int local = t - OFF[a];
  const void* s = sp.p[a];
  ushort v;
  if (flag[0]) v = f2bf(((const float*)s)[local]);
  else         v = ((const ushort*)s)[local];
  dst[t] = v;
}

// =====================================================================
// 0c) pack W into per-tile B-fragment-linear blobs
// =====================================================================
__global__ void packw_kernel(const ushort* __restrict__ wa, ushort* __restrict__ wp) {
  int c = blockIdx.x * 256 + threadIdx.x;
  if (c >= 8 * 2304) return;
  int blob = c / 2304, s = c - blob * 2304;
  int kk = s / 384, r = s - kk * 384;
  int nt = r >> 6, l = r & 63;
  int l16 = l & 15, qd = l >> 4;
  int col, base;
  if (blob < 6) { int z = blob >> 1, half = blob & 1;
                  col = z * 192 + half * 96 + nt * 16 + l16; base = WA_WQKV; }
  else          { col = (blob - 6) * 96 + nt * 16 + l16;     base = WA_WPROJ; }
  short8 pk = *(const short8*)(wa + base + (size_t)col * 192 + kk * 32 + qd * 8);
  *(short8*)(wp + (size_t)c * 8) = pk;
}

// =====================================================================
// 0d) pack y into A-fragment-linear tiles
// =====================================================================
__global__ __launch_bounds__(256) void packa_kernel(const void* __restrict__ src,
                                                    ushort* __restrict__ dst,
                                                    const int* __restrict__ flag) {
  int c = blockIdx.x * 256 + threadIdx.x;
  int tile = c / 3072, cc = c - tile * 3072;
  int kk = cc / 512, c2 = cc - kk * 512;
  int rowhi = c2 / 64, c3 = c2 - rowhi * 64;
  int q = c3 >> 4, l16 = c3 & 15;
  size_t M = (size_t)tile * 128 + rowhi * 16 + l16;
  size_t so = M * 192 + kk * 32 + q * 8;
  short8 pk;
  if (flag[0]) {
    float4_ lo = *(const float4_*)((const float*)src + so);
    float4_ hi = *(const float4_*)((const float*)src + so + 4);
#pragma unroll
    for (int j = 0; j < 4; ++j) {
      pk[j]     = (short)f2bf(lo[j]);
      pk[4 + j] = (short)f2bf(hi[j]);
    }
  } else {
    pk = *(const short8*)((const ushort*)src + so);
  }
  *(short8*)(dst + (size_t)c * 8) = pk;
}

// =====================================================================
// 1) pos MLP (standalone, tiny): offsets (1331,3) -> pos (1331,6) fp32
// =====================================================================
__device__ __forceinline__ void ln_relu(const float* p, const ushort* g,
                                        const ushort* b, float* r) {
  float m = 0.f;
#pragma unroll
  for (int t = 0; t < 12; ++t) m += p[t];
  m *= (1.f / 12.f);
  float v = 0.f;
#pragma unroll
  for (int t = 0; t < 12; ++t) { float d = p[t] - m; v += d * d; }
  v *= (1.f / 12.f);
  float inv = rsqrtf(v + 1e-5f);
#pragma unroll
  for (int t = 0; t < 12; ++t) {
    float z = (p[t] - m) * inv * bf2f(g[t]) + bf2f(b[t]);
    r[t] = fmaxf(z, 0.f);
  }
}

__global__ void pos_mlp_kernel(const ushort* __restrict__ wa, float* __restrict__ pos) {
  int m = blockIdx.x * blockDim.x + threadIdx.x;
  if (m >= 1331) return;
  const ushort* pw  = wa + WA_PPW;  const ushort* pb  = wa + WA_PPB;
  const ushort* g1  = wa + WA_G1;   const ushort* b1  = wa + WA_B1;
  const ushort* w1  = wa + WA_W1;   const ushort* wb1 = wa + WA_WB1;
  const ushort* g2  = wa + WA_G2;   const ushort* b2  = wa + WA_B2;
  const ushort* w2  = wa + WA_W2;   const ushort* wb2 = wa + WA_WB2;
  const ushort* g3  = wa + WA_G3;   const ushort* b3  = wa + WA_B3;
  const ushort* w3  = wa + WA_W3;   const ushort* wb3 = wa + WA_WB3;

  int ih = m / 121, rem = m - ih * 121;
  int iw = rem / 11, id = rem - iw * 11;
  float fh = (float)(ih - 5), fw = (float)(iw - 5), fd = (float)(id - 5);
  float p[12], r[12], q[12];
#pragma unroll
  for (int t = 0; t < 12; ++t)
    p[t] = fh * bf2f(pw[t * 3]) + fw * bf2f(pw[t * 3 + 1]) +
           fd * bf2f(pw[t * 3 + 2]) + bf2f(pb[t]);
  ln_relu(p, g1, b1, r);
#pragma unroll
  for (int t = 0; t < 12; ++t) {
    float s = bf2f(wb1[t]);
#pragma unroll
    for (int u = 0; u < 12; ++u) s += r[u] * bf2f(w1[t * 12 + u]);
    q[t] = s;
  }
  ln_relu(q, g2, b2, r);
#pragma unroll
  for (int t = 0; t < 12; ++t) {
    float s = bf2f(wb2[t]);
#pragma unroll
    for (int u = 0; u < 12; ++u) s += r[u] * bf2f(w2[t * 12 + u]);
    p[t] = s;
  }
  ln_relu(p, g3, b3, r);
#pragma unroll
  for (int h = 0; h < 6; ++h) {
    float s = bf2f(wb3[h]);
#pragma unroll
    for (int u = 0; u < 12; ++u) s += r[u] * bf2f(w3[h * 12 + u]);
    pos[m * 6 + h] = s;
  }
}

// =====================================================================
// 2a) rpb fragments (transposed S^T layout), reading pos from global
// =====================================================================
__global__ void rpbfrag_kernel(const float* __restrict__ pos, ushort* __restrict__ out) {
  int tgl = blockIdx.x * 256 + threadIdx.x;
  if (tgl >= 6 * 196 * 64) return;
  int lane = tgl & 63;
  int tj   = (tgl >> 6) % 196;
  int h    = (tgl >> 6) / 196;
  int tt = tj / 14, jt = tj - tt * 14;
  int l16 = lane & 15, quad = lane >> 4;
  int i = tt * 16 + l16;
  int jbase = jt * 16 + quad * 4;
  ushort4_ o;
  if (i < 216 && jbase < 216) {
    int h1 = i / 36, r1 = i - h1 * 36, w1 = r1 / 6, d1 = r1 - w1 * 6;
#pragma unroll
    for (int r = 0; r < 4; ++r) {
      int j = jbase + r;
      int h2 = j / 36, r2 = j - h2 * 36, w2 = r2 / 6, d2 = r2 - w2 * 6;
      int idx = ((h1 - h2 + 5) * 11 + (w1 - w2 + 5)) * 11 + (d1 - d2 + 5);
      o[r] = f2bf(pos[idx * 6 + h]);
    }
  } else {
#pragma unroll
    for (int r = 0; r < 4; ++r) o[r] = f2bf(PADV);
  }
  *(ushort4_*)(out + (size_t)tgl * 4) = o;
}

// =====================================================================
// 2b) mask fragments, transposed layout
// =====================================================================
__global__ void maskfrag_kernel(const void* __restrict__ maskv,
                                const int* __restrict__ flag,
                                ushort* __restrict__ out) {
  int tgl = blockIdx.x * 256 + threadIdx.x;
  if (tgl >= 64 * 196 * 64) return;
  bool mf32 = flag[0] != 0;
  int lane = tgl & 63;
  int tj   = (tgl >> 6) % 196;
  int g    = (tgl >> 6) / 196;
  int tt = tj / 14, jt = tj - tt * 14;
  int l16 = lane & 15, quad = lane >> 4;
  int i = tt * 16 + l16;
  int jbase = jt * 16 + quad * 4;
  ushort4_ o;
  if (i < 216 && jbase < 216) {
    int mi = i * 216 + jbase;
    if (mf32) {
      float4_ mv = *(const float4_*)((const float*)maskv + (size_t)g * NSQ + mi);
#pragma unroll
      for (int r = 0; r < 4; ++r) o[r] = f2bf(mv[r]);
    } else {
      o = *(const ushort4_*)((const ushort*)maskv + (size_t)g * NSQ + mi);
    }
  } else {
#pragma unroll
    for (int r = 0; r < 4; ++r) o[r] = f2bf(PADV);
  }
  *(ushort4_*)(out + (size_t)tgl * 4) = o;
}

// =====================================================================
// 3) GEMM v3: M-tile 128, N-tile 96, K=192.
//    A: packed-coalesced (yf) for z=1,2; row-major for z=0 / proj.
//    B: contiguous copy from packed blob -> conflict-free LDS.
// =====================================================================
__global__ __launch_bounds__(256, 2) void gemm_kernel(
    const void* __restrict__ Arow,        // x (qkv z=0) / opre (proj)
    const ushort* __restrict__ Apack,     // yf (qkv z=1,2)
    const ushort* __restrict__ wpacked,
    const ushort* __restrict__ bias,
    void* __restrict__ dq, void* __restrict__ dk, void* __restrict__ dv,
    const int* __restrict__ flag, int is_proj) {
  __shared__ __align__(16) ushort b_lds[2304 * 8];

  int tid = threadIdx.x;
  int tile = blockIdx.x;
  int m0 = tile * 128;
  int half = blockIdx.y;
  int n0 = half * 96;
  int z  = blockIdx.z;
  int blob = is_proj ? (6 + half) : (z * 2 + half);
  float scale = (!is_proj && z == 0) ? 0.17677669529663687f : 1.0f;
  void* dst = (z == 0) ? dq : (z == 1 ? dk : dv);
  int fl = flag[0];
  bool a_packed = (!is_proj) && (z != 0);
  bool f32path = (!is_proj) && (z == 0) && (fl != 0);
  bool o_f32 = is_proj && (fl != 0);

  int lane = tid & 63, w = tid >> 6;
  int l16 = lane & 15, quad = lane >> 4;

  // ---- A fragments ----
  short8 af[6][2];
  if (a_packed) {
    const ushort* tb = Apack + (size_t)tile * 24576 + lane * 8;
#pragma unroll
    for (int kk = 0; kk < 6; ++kk)
#pragma unroll
      for (int mt = 0; mt < 2; ++mt)
        af[kk][mt] = *(const short8*)(tb + kk * 4096 + (w * 2 + mt) * 512);
  } else if (f32path) {
#pragma unroll
    for (int kk = 0; kk < 6; ++kk)
#pragma unroll
      for (int mt = 0; mt < 2; ++mt) {
        const float* Af = (const float*)Arow +
            (size_t)(m0 + w * 32 + mt * 16 + l16) * 192 + kk * 32 + quad * 8;
        float4_ lo = *(const float4_*)Af;
        float4_ hi = *(const float4_*)(Af + 4);
#pragma unroll
        for (int j = 0; j < 4; ++j) {
          af[kk][mt][j]     = (short)f2bf(lo[j]);
          af[kk][mt][4 + j] = (short)f2bf(hi[j]);
        }
      }
  } else {
#pragma unroll
    for (int kk = 0; kk < 6; ++kk)
#pragma unroll
      for (int mt = 0; mt < 2; ++mt)
        af[kk][mt] = *(const short8*)((const ushort*)Arow +
            (size_t)(m0 + w * 32 + mt * 16 + l16) * 192 + kk * 32 + quad * 8);
  }

  // ---- stage B: contiguous blob copy ----
  {
    const ushort* wb = wpacked + (size_t)blob * 18432;
#pragma unroll
    for (int it = 0; it < 9; ++it) {
      int s = tid + it * 256;
      *(short8*)(b_lds + s * 8) = *(const short8*)(wb + s * 8);
    }
  }
  __syncthreads();

  float4_ acc[2][6];
#pragma unroll
  for (int mt = 0; mt < 2; ++mt)
#pragma unroll
    for (int nt = 0; nt < 6; ++nt) acc[mt][nt] = (float4_){0.f, 0.f, 0.f, 0.f};

#pragma unroll
  for (int kk = 0; kk < 6; ++kk) {
    short8 bfr[6];
#pragma unroll
    for (int nt = 0; nt < 6; ++nt)
      bfr[nt] = *(const short8*)(b_lds + ((kk * 6 + nt) * 64 + lane) * 8);
#pragma unroll
    for (int mt = 0; mt < 2; ++mt)
#pragma unroll
      for (int nt = 0; nt < 6; ++nt)
        acc[mt][nt] = __builtin_amdgcn_mfma_f32_16x16x32_bf16(af[kk][mt], bfr[nt], acc[mt][nt], 0, 0, 0);
  }

#pragma unroll
  for (int mt = 0; mt < 2; ++mt) {
#pragma unroll
    for (int nt = 0; nt < 6; ++nt) {
      int lcol = n0 + nt * 16 + l16;
      float bv = bf2f(bias[(is_proj ? 0 : z * 192) + lcol]);
#pragma unroll
      for (int r = 0; r < 4; ++r) {
        int grow = m0 + w * 32 + mt * 16 + quad * 4 + r;
        float val = (acc[mt][nt][r] + bv) * scale;
        if (is_proj) {
          if (o_f32) ((float*)dst)[(size_t)grow * 192 + lcol] = val;
          else       ((ushort*)dst)[(size_t)grow * 192 + lcol] = f2bf(val);
        } else {
          int bb = grow / 216;
          int nn2 = grow - bb * 216;
          int hh = lcol >> 5, dd = lcol & 31;
          ((ushort*)dst)[(((size_t)bb * 6 + hh) * 216 + nn2) * 32 + dd] = f2bf(val);
        }
      }
    }
  }
}

// =====================================================================
// 4) fused attention v2 (S^T trick)
// =====================================================================
__global__ __launch_bounds__(256) void attn_kernel(
    const ushort* __restrict__ q, const ushort* __restrict__ k,
    const ushort* __restrict__ v, const ushort* __restrict__ rpbf,
    const ushort* __restrict__ maskf, ushort* __restrict__ opre) {
#if HAVE_MFMA16
  __shared__ __align__(16) ushort vfrag[28 * 64 * 4];
#else
  __shared__ __align__(16) ushort vfrag[14 * 64 * 8];
#endif

  int bid = blockIdx.x;
  int b = bid / 6, h = bid - b * 6;
  int g = b & 63;
  int tid = threadIdx.x, lane = tid & 63, w = tid >> 6;
  int l16 = lane & 15, quad = lane >> 4;

  const ushort* qh = q + (size_t)(b * 6 + h) * 6912;
  const ushort* kh = k + (size_t)(b * 6 + h) * 6912;
  const ushort* vh = v + (size_t)(b * 6 + h) * 6912;

#if HAVE_MFMA16
  for (int pos = tid; pos < 1792; pos += 256) {
    int chunk = pos >> 6, l = pos & 63;
    int kt = chunk >> 1, dh = chunk & 1;
    int qd = l >> 4, lv = l & 15;
    ushort4_ tmp;
#pragma unroll
    for (int j = 0; j < 4; ++j)
      tmp[j] = vh[(kt * 16 + qd * 4 + j) * 32 + dh * 16 + lv];
    *(ushort4_*)(vfrag + pos * 4) = tmp;
  }
#else
  for (int pos = tid; pos < 896; pos += 256) {
    int chunk = pos >> 6, l = pos & 63;
    int kt2 = chunk >> 1, dh = chunk & 1;
    int qd = l >> 4, lv = l & 15;
    short8 tmp;
#pragma unroll
    for (int j = 0; j < 8; ++j)
      tmp[j] = (short)vh[(kt2 * 32 + qd * 8 + j) * 32 + dh * 16 + lv];
    *(short8*)(vfrag + pos * 8) = tmp;
  }
#endif
  __syncthreads();

  for (int t = w; t < 14; t += 4) {
    int r0 = t * 16;
    const ushort* rf = rpbf  + ((size_t)(h * 196 + t * 14) * 64 + lane) * 4;
    const ushort* mf = maskf + ((size_t)(g * 196 + t * 14) * 64 + lane) * 4;
    short8 aq = *(const short8*)(qh + (r0 + l16) * 32 + quad * 8);

    float4_ st[14];
#pragma unroll
    for (int jt = 0; jt < 14; ++jt) {
      ushort4_ rb = *(const ushort4_*)(rf + jt * 256);
      ushort4_ mb = *(const ushort4_*)(mf + jt * 256);
      float4_ cin;
#pragma unroll
      for (int r = 0; r < 4; ++r) cin[r] = bf2f(rb[r]) + bf2f(mb[r]);
      short8 bk = *(const short8*)(kh + (jt * 16 + l16) * 32 + quad * 8);
      st[jt] = __builtin_amdgcn_mfma_f32_16x16x32_bf16(bk, aq, cin, 0, 0, 0);
    }

    float mx = -1e30f;
#pragma unroll
    for (int jt = 0; jt < 14; ++jt)
#pragma unroll
      for (int r = 0; r < 4; ++r) mx = fmaxf(mx, st[jt][r]);
    mx = fmaxf(mx, __shfl_xor(mx, 16));
    mx = fmaxf(mx, __shfl_xor(mx, 32));
    float sum = 0.f;
#pragma unroll
    for (int jt = 0; jt < 14; ++jt)
#pragma unroll
      for (int r = 0; r < 4; ++r) {
        float pe = __expf(st[jt][r] - mx);
        st[jt][r] = pe;
        sum += pe;
      }
    sum += __shfl_xor(sum, 16);
    sum += __shfl_xor(sum, 32);
    float inv = 1.0f / sum;

    float4_ o0 = (float4_){0.f, 0.f, 0.f, 0.f};
    float4_ o1 = (float4_){0.f, 0.f, 0.f, 0.f};

#if HAVE_MFMA16
#pragma unroll
    for (int kt = 0; kt < 14; ++kt) {
      short4_ pa;
#pragma unroll
      for (int r = 0; r < 4; ++r) pa[r] = (short)f2bf(st[kt][r]);
      short4_ vb0 = *(const short4_*)(vfrag + ((kt * 2 + 0) * 64 + lane) * 4);
      short4_ vb1 = *(const short4_*)(vfrag + ((kt * 2 + 1) * 64 + lane) * 4);
      o0 = MFMA16(pa, vb0, o0);
      o1 = MFMA16(pa, vb1, o1);
    }
#else
#pragma unroll
    for (int kt2 = 0; kt2 < 7; ++kt2) {
      uint pe0 = ((uint)f2bf(st[2*kt2][0])) | (((uint)f2bf(st[2*kt2][1])) << 16);
      uint pe1 = ((uint)f2bf(st[2*kt2][2])) | (((uint)f2bf(st[2*kt2][3])) << 16);
      uint po0 = ((uint)f2bf(st[2*kt2+1][0])) | (((uint)f2bf(st[2*kt2+1][1])) << 16);
      uint po1 = ((uint)f2bf(st[2*kt2+1][2])) | (((uint)f2bf(st[2*kt2+1][3])) << 16);
      int slo = (((2 * quad) & 3) << 4) | l16;
      int shi = (((2 * quad + 1) & 3) << 4) | l16;
      uint e_lo0 = __shfl((int)pe0, slo), e_lo1 = __shfl((int)pe1, slo);
      uint o_lo0 = __shfl((int)po0, slo), o_lo1 = __shfl((int)po1, slo);
      uint e_hi0 = __shfl((int)pe0, shi), e_hi1 = __shfl((int)pe1, shi);
      uint o_hi0 = __shfl((int)po0, shi), o_hi1 = __shfl((int)po1, shi);
      uint lo0 = (quad < 2) ? e_lo0 : o_lo0, lo1 = (quad < 2) ? e_lo1 : o_lo1;
      uint hi0 = (quad < 2) ? e_hi0 : o_hi0, hi1 = (quad < 2) ? e_hi1 : o_hi1;
      uint4 paw = {lo0, lo1, hi0, hi1};
      short8 pa = __builtin_bit_cast(short8, paw);
      short8 vb0 = *(const short8*)(vfrag + ((kt2 * 2 + 0) * 64 + lane) * 8);
      short8 vb1 = *(const short8*)(vfrag + ((kt2 * 2 + 1) * 64 + lane) * 8);
      o0 = __builtin_amdgcn_mfma_f32_16x16x32_bf16(pa, vb0, o0, 0, 0, 0);
      o1 = __builtin_amdgcn_mfma_f32_16x16x32_bf16(pa, vb1, o1, 0, 0, 0);
    }
#endif

#pragma unroll
    for (int r = 0; r < 4; ++r) {
      float ir = __shfl(inv, quad * 4 + r);
      int i = r0 + quad * 4 + r;
      if (i < 216) {
        size_t base = ((size_t)b * 216 + i) * 192 + h * 32;
        opre[base + l16]      = f2bf(o0[r] * ir);
        opre[base + 16 + l16] = f2bf(o1[r] * ir);
      }
    }
  }
}

// =====================================================================
// launch
// =====================================================================
extern "C" void kernel_launch(void* const* d_in, const int* in_sizes, int n_in,
                              void* d_out, int out_size, void* d_ws, size_t ws_size,
                              hipStream_t stream) {
  (void)in_sizes; (void)n_in; (void)out_size; (void)ws_size;

  char* p = (char*)d_ws;
  int*    flag    = (int*)p;           p += 256;
  ushort* warena  = (ushort*)p;        p += 298240;
  ushort* wpacked = (ushort*)p;        p += 294912;
  float*  pos     = (float*)p;         p += 32768;
  ushort* rpbf    = (ushort*)p;        p += 602112;
  ushort* maskf   = (ushort*)p;        p += 6422528;
  ushort* yf      = (ushort*)p;        p += 21234688;  // aliased as opre after QKV GEMM
  ushort* qb      = (ushort*)p;        p += 21234688;
  ushort* kb      = (ushort*)p;        p += 21234688;
  ushort* vb      = (ushort*)p;
  ushort* opre    = yf;

  detect_kernel<<<1, 64, 0, stream>>>((const uint*)d_in[0], flag);

  SrcPtrs sp;
  for (int i = 0; i < 18; ++i) sp.p[i] = d_in[3 + i];
  convert_kernel<<<(WA_TOTAL + 255) / 256, 256, 0, stream>>>(sp, warena, flag);
  packw_kernel<<<72, 256, 0, stream>>>(warena, wpacked);

  packa_kernel<<<5184, 256, 0, stream>>>(d_in[1], yf, flag);

  pos_mlp_kernel<<<6, 256, 0, stream>>>(warena, pos);
  rpbfrag_kernel<<<294, 256, 0, stream>>>(pos, rpbf);
  maskfrag_kernel<<<3136, 256, 0, stream>>>(d_in[2], flag, maskf);

  gemm_kernel<<<dim3(432, 2, 3), 256, 0, stream>>>(
      d_in[0], yf, wpacked, warena + WA_BQKV, qb, kb, vb, flag, 0);

  attn_kernel<<<1536, 256, 0, stream>>>(qb, kb, vb, rpbf, maskf, opre);

  gemm_kernel<<<dim3(432, 2, 1), 256, 0, stream>>>(
      opre, yf, wpacked, warena + WA_BPROJ,
      d_out, d_out, d_out, flag, 1);
}